// Round 1
// baseline (791.903 us; speedup 1.0000x reference)
//
#include <hip/hip_runtime.h>
#include <stdint.h>

// Segment-routed MLP: out[n] = W2[s]@relu(W1[s]@x[n]+b1[s])+b2[s], s=segment_ids[n]
// Strategy: bucket tokens by segment, then two grouped bf16-MFMA GEMMs with an
// intermediate bf16 activation buffer in workspace (32 MB + 32 KB of d_ws).

#define N_SEG 16
#define HID   1024
#define MLPD  4096

typedef __attribute__((ext_vector_type(8))) short bf16x8;
typedef __attribute__((ext_vector_type(4))) float f32x4;

// f32 -> bf16 round-to-nearest-even (finite inputs)
static __device__ __forceinline__ short f2bf(float f) {
  union { float f; unsigned u; } c; c.f = f;
  unsigned u = c.u;
  return (short)((u + 0x7FFFu + ((u >> 16) & 1u)) >> 16);
}

// byte offset into a [rows][64] bf16 LDS tile (128 B row stride), XOR-swizzled
// to kill the 32-way bank conflict of stride-128B column reads (guide G4).
static __device__ __forceinline__ int swz(int row, int col) {
  return ((row << 7) + (col << 1)) ^ ((row & 7) << 4);
}

__global__ void build_index_kernel(const int* __restrict__ seg, int n,
                                   int* __restrict__ offs, int* __restrict__ sidx) {
  __shared__ int cnt[N_SEG];
  __shared__ int cur[N_SEG];
  const int tid = threadIdx.x;
  if (tid < N_SEG) cnt[tid] = 0;
  __syncthreads();
  for (int i = tid; i < n; i += blockDim.x) atomicAdd(&cnt[seg[i]], 1);
  __syncthreads();
  if (tid == 0) {
    int a = 0;
    for (int s = 0; s < N_SEG; ++s) { offs[s] = a; cur[s] = a; a += cnt[s]; }
    offs[N_SEG] = a;
  }
  __syncthreads();
  for (int i = tid; i < n; i += blockDim.x) {
    int s = seg[i];
    int p = atomicAdd(&cur[s], 1);
    sidx[p] = i;
  }
}

// GEMM1: inter[t, n] = relu(x[tok(t), :] @ W1[s][n, :] + b1[s][n]), bf16 out.
// Tile 128x128, BK=64, 4 waves of 64x64 each.
__global__ __launch_bounds__(256)
void gemm1_kernel(const float* __restrict__ x, const float* __restrict__ W1,
                  const float* __restrict__ b1, const int* __restrict__ offs,
                  const int* __restrict__ sidx, short* __restrict__ inter) {
  __shared__ short As[128 * 64];
  __shared__ short Bs[128 * 64];
  char* Asb = (char*)As;
  char* Bsb = (char*)Bs;
  const int s = blockIdx.y;
  const int ntile = blockIdx.x * 128;
  const int segoff = offs[s];
  const int cnt = offs[s + 1] - segoff;
  const int tid = threadIdx.x;
  const int lane = tid & 63, w = tid >> 6;
  const int wr = w >> 1, wc = w & 1;
  const int fr = lane & 15, fq = lane >> 4;
  const int tr = tid >> 3;          // staging row 0..31
  const int tc = (tid & 7) << 3;    // staging col 0..56 step 8
  const float* Wbase = W1 + ((size_t)s * MLPD + ntile) * HID;

  for (int mt = blockIdx.z; mt * 128 < cnt; mt += gridDim.z) {
    const int m0 = mt * 128;
    int tok[4];
#pragma unroll
    for (int i = 0; i < 4; ++i) {
      int r = m0 + tr + i * 32;
      tok[i] = (r < cnt) ? sidx[segoff + r] : -1;
    }
    f32x4 acc[4][4];
#pragma unroll
    for (int m = 0; m < 4; ++m)
#pragma unroll
      for (int n = 0; n < 4; ++n) acc[m][n] = (f32x4){0.f, 0.f, 0.f, 0.f};

    for (int k0 = 0; k0 < HID; k0 += 64) {
      __syncthreads();
      // stage A (gathered x rows, f32 -> bf16)
#pragma unroll
      for (int i = 0; i < 4; ++i) {
        int row = tr + i * 32;
        bf16x8 v;
        if (tok[i] >= 0) {
          const float4* p = (const float4*)(x + (size_t)tok[i] * HID + (k0 + tc));
          float4 u0 = p[0], u1 = p[1];
          v[0] = f2bf(u0.x); v[1] = f2bf(u0.y); v[2] = f2bf(u0.z); v[3] = f2bf(u0.w);
          v[4] = f2bf(u1.x); v[5] = f2bf(u1.y); v[6] = f2bf(u1.z); v[7] = f2bf(u1.w);
        } else {
#pragma unroll
          for (int j = 0; j < 8; ++j) v[j] = 0;
        }
        *(bf16x8*)(Asb + swz(row, tc)) = v;
      }
      // stage B (W1 rows = output cols, f32 -> bf16)
#pragma unroll
      for (int i = 0; i < 4; ++i) {
        int row = tr + i * 32;
        const float4* p = (const float4*)(Wbase + (size_t)row * HID + (k0 + tc));
        float4 u0 = p[0], u1 = p[1];
        bf16x8 v;
        v[0] = f2bf(u0.x); v[1] = f2bf(u0.y); v[2] = f2bf(u0.z); v[3] = f2bf(u0.w);
        v[4] = f2bf(u1.x); v[5] = f2bf(u1.y); v[6] = f2bf(u1.z); v[7] = f2bf(u1.w);
        *(bf16x8*)(Bsb + swz(row, tc)) = v;
      }
      __syncthreads();
#pragma unroll
      for (int kk = 0; kk < 2; ++kk) {
        const int lk = kk * 32 + fq * 8;
        bf16x8 a[4], b[4];
#pragma unroll
        for (int m = 0; m < 4; ++m)
          a[m] = *(const bf16x8*)(Asb + swz(wr * 64 + m * 16 + fr, lk));
#pragma unroll
        for (int n = 0; n < 4; ++n)
          b[n] = *(const bf16x8*)(Bsb + swz(wc * 64 + n * 16 + fr, lk));
#pragma unroll
        for (int m = 0; m < 4; ++m)
#pragma unroll
          for (int n = 0; n < 4; ++n)
            acc[m][n] = __builtin_amdgcn_mfma_f32_16x16x32_bf16(a[m], b[n], acc[m][n], 0, 0, 0);
      }
    }
    // epilogue: +bias, relu, bf16 store to compact inter
#pragma unroll
    for (int n = 0; n < 4; ++n) {
      const int col = ntile + wc * 64 + n * 16 + fr;
      const float bias = b1[s * MLPD + col];
#pragma unroll
      for (int m = 0; m < 4; ++m) {
#pragma unroll
        for (int j = 0; j < 4; ++j) {
          int r = m0 + wr * 64 + m * 16 + fq * 4 + j;
          if (r < cnt) {
            float y = acc[m][n][j] + bias;
            y = y > 0.f ? y : 0.f;
            inter[(size_t)(segoff + r) * MLPD + col] = f2bf(y);
          }
        }
      }
    }
  }
}

// GEMM2: out[tok(t), n] = inter[t, :] @ W2[s][n, :] + b2[s][n], f32 scatter.
// Tile 128x64 (NT=64 for 2 blocks/CU), BK=64, 4 waves of 32x64.
__global__ __launch_bounds__(256)
void gemm2_kernel(const short* __restrict__ inter, const float* __restrict__ W2,
                  const float* __restrict__ b2, const int* __restrict__ offs,
                  const int* __restrict__ sidx, float* __restrict__ out) {
  __shared__ short As[128 * 64];
  __shared__ short Bs[64 * 64];
  char* Asb = (char*)As;
  char* Bsb = (char*)Bs;
  const int s = blockIdx.y;
  const int ntile = blockIdx.x * 64;
  const int segoff = offs[s];
  const int cnt = offs[s + 1] - segoff;
  const int tid = threadIdx.x;
  const int lane = tid & 63, w = tid >> 6;
  const int fr = lane & 15, fq = lane >> 4;
  const int tr = tid >> 3;
  const int tc = (tid & 7) << 3;
  const float* Wbase = W2 + ((size_t)s * HID + ntile) * MLPD;

  for (int mt = blockIdx.z; mt * 128 < cnt; mt += gridDim.z) {
    const int m0 = mt * 128;
    f32x4 acc[2][4];
#pragma unroll
    for (int m = 0; m < 2; ++m)
#pragma unroll
      for (int n = 0; n < 4; ++n) acc[m][n] = (f32x4){0.f, 0.f, 0.f, 0.f};

    for (int k0 = 0; k0 < MLPD; k0 += 64) {
      __syncthreads();
      // stage A (inter is already bf16, dense in sorted order)
#pragma unroll
      for (int i = 0; i < 4; ++i) {
        int row = tr + i * 32;
        int r = m0 + row;
        bf16x8 v;
        if (r < cnt) {
          v = *(const bf16x8*)(inter + (size_t)(segoff + r) * MLPD + (k0 + tc));
        } else {
#pragma unroll
          for (int j = 0; j < 8; ++j) v[j] = 0;
        }
        *(bf16x8*)(Asb + swz(row, tc)) = v;
      }
      // stage B (W2 rows = output cols, f32 -> bf16); only 64 rows
#pragma unroll
      for (int i = 0; i < 2; ++i) {
        int row = tr + i * 32;
        const float4* p = (const float4*)(Wbase + (size_t)row * MLPD + (k0 + tc));
        float4 u0 = p[0], u1 = p[1];
        bf16x8 v;
        v[0] = f2bf(u0.x); v[1] = f2bf(u0.y); v[2] = f2bf(u0.z); v[3] = f2bf(u0.w);
        v[4] = f2bf(u1.x); v[5] = f2bf(u1.y); v[6] = f2bf(u1.z); v[7] = f2bf(u1.w);
        *(bf16x8*)(Bsb + swz(row, tc)) = v;
      }
      __syncthreads();
#pragma unroll
      for (int kk = 0; kk < 2; ++kk) {
        const int lk = kk * 32 + fq * 8;
        bf16x8 a[2], b[4];
#pragma unroll
        for (int m = 0; m < 2; ++m)
          a[m] = *(const bf16x8*)(Asb + swz(w * 32 + m * 16 + fr, lk));
#pragma unroll
        for (int n = 0; n < 4; ++n)
          b[n] = *(const bf16x8*)(Bsb + swz(n * 16 + fr, lk));
#pragma unroll
        for (int m = 0; m < 2; ++m)
#pragma unroll
          for (int n = 0; n < 4; ++n)
            acc[m][n] = __builtin_amdgcn_mfma_f32_16x16x32_bf16(a[m], b[n], acc[m][n], 0, 0, 0);
      }
    }
    // epilogue: +bias, scatter f32 rows back to token order
#pragma unroll
    for (int n = 0; n < 4; ++n) {
      const int col = ntile + n * 16 + fr;
      const float bias = b2[s * HID + col];
#pragma unroll
      for (int m = 0; m < 2; ++m) {
#pragma unroll
        for (int j = 0; j < 4; ++j) {
          int r = m0 + w * 32 + m * 16 + fq * 4 + j;
          if (r < cnt) {
            int tk = sidx[segoff + r];
            out[(size_t)tk * HID + col] = acc[m][n][j] + bias;
          }
        }
      }
    }
  }
}

extern "C" void kernel_launch(void* const* d_in, const int* in_sizes, int n_in,
                              void* d_out, int out_size, void* d_ws, size_t ws_size,
                              hipStream_t stream) {
  const float* x  = (const float*)d_in[0];
  const int*   seg = (const int*)d_in[1];
  const float* W1 = (const float*)d_in[2];
  const float* W2 = (const float*)d_in[3];
  const float* b1 = (const float*)d_in[4];
  const float* b2 = (const float*)d_in[5];
  float* out = (float*)d_out;
  const int n_tok = in_sizes[1];

  // workspace layout: [0,128): offs (17 ints); [128, 128+4*n): sidx;
  // [32768, 32768+2*N*MLP): bf16 intermediate activations (32 MB @ N=4096)
  int* offs = (int*)d_ws;
  int* sidx = offs + 32;
  short* inter = (short*)((char*)d_ws + 32768);

  build_index_kernel<<<1, 256, 0, stream>>>(seg, n_tok, offs, sidx);
  gemm1_kernel<<<dim3(MLPD / 128, N_SEG, 4), 256, 0, stream>>>(x, W1, b1, offs, sidx, inter);
  gemm2_kernel<<<dim3(HID / 64, N_SEG, 4), 256, 0, stream>>>(inter, W2, b2, offs, sidx, out);
}

// Round 2
// 782.121 us; speedup vs baseline: 1.0125x; 1.0125x over previous
//
#include <hip/hip_runtime.h>
#include <stdint.h>

// Segment-routed MLP: out[n] = W2[s]@relu(W1[s]@x[n]+b1[s])+b2[s], s=segment_ids[n]
// Strategy: bucket tokens by segment, then two grouped bf16-MFMA GEMMs with an
// intermediate bf16 activation buffer in workspace (32 MB + 32 KB of d_ws).
// R2 change: f32->bf16 conversion via native __bf16 cast so the compiler emits
// v_cvt_pk_bf16_f32 (1 inst / 2 elems) instead of ~5-op bit-twiddle RNE; the
// R1 profile showed staging VALU (not MFMA, not HBM) was the limiter.

#define N_SEG 16
#define HID   1024
#define MLPD  4096

typedef __attribute__((ext_vector_type(8))) short bf16x8;
typedef __attribute__((ext_vector_type(4))) float f32x4;

// f32 -> bf16 via hardware converter (v_cvt_pk_bf16_f32 when paired)
static __device__ __forceinline__ short f2bf(float f) {
  union { __bf16 h; short s; } u;
  u.h = (__bf16)f;
  return u.s;
}

static __device__ __forceinline__ bf16x8 cvt8(float4 u0, float4 u1) {
  bf16x8 v;
  v[0] = f2bf(u0.x); v[1] = f2bf(u0.y); v[2] = f2bf(u0.z); v[3] = f2bf(u0.w);
  v[4] = f2bf(u1.x); v[5] = f2bf(u1.y); v[6] = f2bf(u1.z); v[7] = f2bf(u1.w);
  return v;
}

// byte offset into a [rows][64] bf16 LDS tile (128 B row stride), XOR-swizzled
// to kill the 32-way bank conflict of stride-128B column reads (guide G4).
static __device__ __forceinline__ int swz(int row, int col) {
  return ((row << 7) + (col << 1)) ^ ((row & 7) << 4);
}

__global__ void build_index_kernel(const int* __restrict__ seg, int n,
                                   int* __restrict__ offs, int* __restrict__ sidx) {
  __shared__ int cnt[N_SEG];
  __shared__ int cur[N_SEG];
  const int tid = threadIdx.x;
  if (tid < N_SEG) cnt[tid] = 0;
  __syncthreads();
  for (int i = tid; i < n; i += blockDim.x) atomicAdd(&cnt[seg[i]], 1);
  __syncthreads();
  if (tid == 0) {
    int a = 0;
    for (int s = 0; s < N_SEG; ++s) { offs[s] = a; cur[s] = a; a += cnt[s]; }
    offs[N_SEG] = a;
  }
  __syncthreads();
  for (int i = tid; i < n; i += blockDim.x) {
    int s = seg[i];
    int p = atomicAdd(&cur[s], 1);
    sidx[p] = i;
  }
}

// GEMM1: inter[t, n] = relu(x[tok(t), :] @ W1[s][n, :] + b1[s][n]), bf16 out.
// Tile 128x128, BK=64, 4 waves of 64x64 each.
__global__ __launch_bounds__(256)
void gemm1_kernel(const float* __restrict__ x, const float* __restrict__ W1,
                  const float* __restrict__ b1, const int* __restrict__ offs,
                  const int* __restrict__ sidx, short* __restrict__ inter) {
  __shared__ short As[128 * 64];
  __shared__ short Bs[128 * 64];
  char* Asb = (char*)As;
  char* Bsb = (char*)Bs;
  const int s = blockIdx.y;
  const int ntile = blockIdx.x * 128;
  const int segoff = offs[s];
  const int cnt = offs[s + 1] - segoff;
  const int tid = threadIdx.x;
  const int lane = tid & 63, w = tid >> 6;
  const int wr = w >> 1, wc = w & 1;
  const int fr = lane & 15, fq = lane >> 4;
  const int tr = tid >> 3;          // staging row 0..31
  const int tc = (tid & 7) << 3;    // staging col 0..56 step 8
  const float* Wbase = W1 + ((size_t)s * MLPD + ntile) * HID;

  for (int mt = blockIdx.z; mt * 128 < cnt; mt += gridDim.z) {
    const int m0 = mt * 128;
    int tok[4];
#pragma unroll
    for (int i = 0; i < 4; ++i) {
      int r = m0 + tr + i * 32;
      tok[i] = (r < cnt) ? sidx[segoff + r] : -1;
    }
    f32x4 acc[4][4];
#pragma unroll
    for (int m = 0; m < 4; ++m)
#pragma unroll
      for (int n = 0; n < 4; ++n) acc[m][n] = (f32x4){0.f, 0.f, 0.f, 0.f};

    for (int k0 = 0; k0 < HID; k0 += 64) {
      __syncthreads();
      // stage A (gathered x rows, f32 -> bf16)
#pragma unroll
      for (int i = 0; i < 4; ++i) {
        int row = tr + i * 32;
        bf16x8 v;
        if (tok[i] >= 0) {
          const float4* p = (const float4*)(x + (size_t)tok[i] * HID + (k0 + tc));
          v = cvt8(p[0], p[1]);
        } else {
#pragma unroll
          for (int j = 0; j < 8; ++j) v[j] = 0;
        }
        *(bf16x8*)(Asb + swz(row, tc)) = v;
      }
      // stage B (W1 rows = output cols, f32 -> bf16)
#pragma unroll
      for (int i = 0; i < 4; ++i) {
        int row = tr + i * 32;
        const float4* p = (const float4*)(Wbase + (size_t)row * HID + (k0 + tc));
        *(bf16x8*)(Bsb + swz(row, tc)) = cvt8(p[0], p[1]);
      }
      __syncthreads();
#pragma unroll
      for (int kk = 0; kk < 2; ++kk) {
        const int lk = kk * 32 + fq * 8;
        bf16x8 a[4], b[4];
#pragma unroll
        for (int m = 0; m < 4; ++m)
          a[m] = *(const bf16x8*)(Asb + swz(wr * 64 + m * 16 + fr, lk));
#pragma unroll
        for (int n = 0; n < 4; ++n)
          b[n] = *(const bf16x8*)(Bsb + swz(wc * 64 + n * 16 + fr, lk));
#pragma unroll
        for (int m = 0; m < 4; ++m)
#pragma unroll
          for (int n = 0; n < 4; ++n)
            acc[m][n] = __builtin_amdgcn_mfma_f32_16x16x32_bf16(a[m], b[n], acc[m][n], 0, 0, 0);
      }
    }
    // epilogue: +bias, relu, bf16 store to compact inter
#pragma unroll
    for (int n = 0; n < 4; ++n) {
      const int col = ntile + wc * 64 + n * 16 + fr;
      const float bias = b1[s * MLPD + col];
#pragma unroll
      for (int m = 0; m < 4; ++m) {
#pragma unroll
        for (int j = 0; j < 4; ++j) {
          int r = m0 + wr * 64 + m * 16 + fq * 4 + j;
          if (r < cnt) {
            float y = acc[m][n][j] + bias;
            y = y > 0.f ? y : 0.f;
            inter[(size_t)(segoff + r) * MLPD + col] = f2bf(y);
          }
        }
      }
    }
  }
}

// GEMM2: out[tok(t), n] = inter[t, :] @ W2[s][n, :] + b2[s][n], f32 scatter.
// Tile 128x64 (NT=64 for 2 blocks/CU), BK=64, 4 waves of 32x64.
__global__ __launch_bounds__(256)
void gemm2_kernel(const short* __restrict__ inter, const float* __restrict__ W2,
                  const float* __restrict__ b2, const int* __restrict__ offs,
                  const int* __restrict__ sidx, float* __restrict__ out) {
  __shared__ short As[128 * 64];
  __shared__ short Bs[64 * 64];
  char* Asb = (char*)As;
  char* Bsb = (char*)Bs;
  const int s = blockIdx.y;
  const int ntile = blockIdx.x * 64;
  const int segoff = offs[s];
  const int cnt = offs[s + 1] - segoff;
  const int tid = threadIdx.x;
  const int lane = tid & 63, w = tid >> 6;
  const int fr = lane & 15, fq = lane >> 4;
  const int tr = tid >> 3;
  const int tc = (tid & 7) << 3;
  const float* Wbase = W2 + ((size_t)s * HID + ntile) * MLPD;

  for (int mt = blockIdx.z; mt * 128 < cnt; mt += gridDim.z) {
    const int m0 = mt * 128;
    f32x4 acc[2][4];
#pragma unroll
    for (int m = 0; m < 2; ++m)
#pragma unroll
      for (int n = 0; n < 4; ++n) acc[m][n] = (f32x4){0.f, 0.f, 0.f, 0.f};

    for (int k0 = 0; k0 < MLPD; k0 += 64) {
      __syncthreads();
      // stage A (inter is already bf16, dense in sorted order)
#pragma unroll
      for (int i = 0; i < 4; ++i) {
        int row = tr + i * 32;
        int r = m0 + row;
        bf16x8 v;
        if (r < cnt) {
          v = *(const bf16x8*)(inter + (size_t)(segoff + r) * MLPD + (k0 + tc));
        } else {
#pragma unroll
          for (int j = 0; j < 8; ++j) v[j] = 0;
        }
        *(bf16x8*)(Asb + swz(row, tc)) = v;
      }
      // stage B (W2 rows = output cols, f32 -> bf16); only 64 rows
#pragma unroll
      for (int i = 0; i < 2; ++i) {
        int row = tr + i * 32;
        const float4* p = (const float4*)(Wbase + (size_t)row * MLPD + (k0 + tc));
        *(bf16x8*)(Bsb + swz(row, tc)) = cvt8(p[0], p[1]);
      }
      __syncthreads();
#pragma unroll
      for (int kk = 0; kk < 2; ++kk) {
        const int lk = kk * 32 + fq * 8;
        bf16x8 a[2], b[4];
#pragma unroll
        for (int m = 0; m < 2; ++m)
          a[m] = *(const bf16x8*)(Asb + swz(w * 32 + m * 16 + fr, lk));
#pragma unroll
        for (int n = 0; n < 4; ++n)
          b[n] = *(const bf16x8*)(Bsb + swz(n * 16 + fr, lk));
#pragma unroll
        for (int m = 0; m < 2; ++m)
#pragma unroll
          for (int n = 0; n < 4; ++n)
            acc[m][n] = __builtin_amdgcn_mfma_f32_16x16x32_bf16(a[m], b[n], acc[m][n], 0, 0, 0);
      }
    }
    // epilogue: +bias, scatter f32 rows back to token order
#pragma unroll
    for (int n = 0; n < 4; ++n) {
      const int col = ntile + n * 16 + fr;
      const float bias = b2[s * HID + col];
#pragma unroll
      for (int m = 0; m < 2; ++m) {
#pragma unroll
        for (int j = 0; j < 4; ++j) {
          int r = m0 + w * 32 + m * 16 + fq * 4 + j;
          if (r < cnt) {
            int tk = sidx[segoff + r];
            out[(size_t)tk * HID + col] = acc[m][n][j] + bias;
          }
        }
      }
    }
  }
}

extern "C" void kernel_launch(void* const* d_in, const int* in_sizes, int n_in,
                              void* d_out, int out_size, void* d_ws, size_t ws_size,
                              hipStream_t stream) {
  const float* x  = (const float*)d_in[0];
  const int*   seg = (const int*)d_in[1];
  const float* W1 = (const float*)d_in[2];
  const float* W2 = (const float*)d_in[3];
  const float* b1 = (const float*)d_in[4];
  const float* b2 = (const float*)d_in[5];
  float* out = (float*)d_out;
  const int n_tok = in_sizes[1];

  // workspace layout: [0,128): offs (17 ints); [128, 128+4*n): sidx;
  // [32768, 32768+2*N*MLP): bf16 intermediate activations (32 MB @ N=4096)
  int* offs = (int*)d_ws;
  int* sidx = offs + 32;
  short* inter = (short*)((char*)d_ws + 32768);

  build_index_kernel<<<1, 256, 0, stream>>>(seg, n_tok, offs, sidx);
  gemm1_kernel<<<dim3(MLPD / 128, N_SEG, 4), 256, 0, stream>>>(x, W1, b1, offs, sidx, inter);
  gemm2_kernel<<<dim3(HID / 64, N_SEG, 4), 256, 0, stream>>>(inter, W2, b2, offs, sidx, out);
}